// Round 2
// baseline (1926.559 us; speedup 1.0000x reference)
//
#include <hip/hip_runtime.h>
#include <hip/hip_bf16.h>

// ---------------------------------------------------------------------------
// TransformerBlock: LN1 -> attn -> +res -> LN2 -> MoE(top1,cap) -> +res
// B=4 T=1024 H=1024 NH=16 DH=64 E=8 CAP=512 S=4096 FF=4096  (all fp32)
// Round 2: same fp32 baseline, workspace cut 112->96 MB (x1 lives in d_out)
// to rule out ws overrun as the container-failure cause.
// ---------------------------------------------------------------------------

#define Bc   4
#define Tc   1024
#define Hc   1024
#define NHc  16
#define DHc  64
#define Ec   8
#define CAPc 512
#define Sc   4096
#define FFc  4096

__device__ __forceinline__ float gelu_exact(float x) {
    return 0.5f * x * (1.0f + erff(x * 0.70710678118654752440f));
}

// ---------------------------- LayerNorm ------------------------------------
__global__ __launch_bounds__(256) void ln_kernel(const float* __restrict__ x,
                                                 const float* __restrict__ w,
                                                 const float* __restrict__ b,
                                                 float* __restrict__ o) {
    const int row = blockIdx.x;
    const int tid = threadIdx.x;
    const float4 v = ((const float4*)(x + (size_t)row * Hc))[tid];
    float s = v.x + v.y + v.z + v.w;
    float q = v.x * v.x + v.y * v.y + v.z * v.z + v.w * v.w;
#pragma unroll
    for (int m = 1; m < 64; m <<= 1) {
        s += __shfl_xor(s, m);
        q += __shfl_xor(q, m);
    }
    __shared__ float ss[4], qq[4];
    if ((tid & 63) == 0) { ss[tid >> 6] = s; qq[tid >> 6] = q; }
    __syncthreads();
    s = ss[0] + ss[1] + ss[2] + ss[3];
    q = qq[0] + qq[1] + qq[2] + qq[3];
    const float mean = s * (1.0f / Hc);
    const float var  = q * (1.0f / Hc) - mean * mean;
    const float inv  = 1.0f / sqrtf(var + 1e-5f);
    const float4 wv = ((const float4*)w)[tid];
    const float4 bv = ((const float4*)b)[tid];
    float4 r;
    r.x = (v.x - mean) * inv * wv.x + bv.x;
    r.y = (v.y - mean) * inv * wv.y + bv.y;
    r.z = (v.z - mean) * inv * wv.z + bv.z;
    r.w = (v.w - mean) * inv * wv.w + bv.w;
    ((float4*)(o + (size_t)row * Hc))[tid] = r;
}

// ---------------------------- GEMM -----------------------------------------
// C[M,N] = A[M,K] @ B + bias (+res / gelu).  BLAYOUT 0: B is [N,K] ("B^T",
// K-contiguous).  BLAYOUT 1: B is [K,N].  EPI 0: +bias.  1: gelu(+bias).
// 2: +bias +res.  Batched over blockIdx.z with element strides.
template <int BLAYOUT, int EPI>
__global__ __launch_bounds__(256) void gemm_k(const float* __restrict__ Ag,
                                              const float* __restrict__ Bg,
                                              const float* __restrict__ biasg,
                                              const float* __restrict__ resg,
                                              float* __restrict__ Cg,
                                              int M, int N, int K,
                                              long long sAe, long long sBe,
                                              long long sCe, long long sBiasE) {
    const int e = blockIdx.z;
    const float* A    = Ag + (size_t)e * sAe;
    const float* B    = Bg + (size_t)e * sBe;
    const float* bias = biasg + (size_t)e * sBiasE;
    float* C          = Cg + (size_t)e * sCe;

    const int m0 = blockIdx.y * 128;
    const int n0 = blockIdx.x * 128;
    const int tid = threadIdx.x;
    const int tx = tid & 15;
    const int ty = tid >> 4;

    __shared__ float As[16][132];  // [k][m], pad 132 keeps 16B align + spreads banks
    __shared__ float Bs[16][132];  // [k][n]

    float acc[8][8];
#pragma unroll
    for (int i = 0; i < 8; ++i)
#pragma unroll
        for (int j = 0; j < 8; ++j) acc[i][j] = 0.0f;

    for (int k0 = 0; k0 < K; k0 += 16) {
        __syncthreads();
        // stage A tile (transpose to [k][m])
#pragma unroll
        for (int jj = 0; jj < 2; ++jj) {
            const int idx = tid + jj * 256;
            const int row = idx >> 2;
            const int kq  = (idx & 3) * 4;
            const float4 v = *(const float4*)(A + (size_t)(m0 + row) * K + (k0 + kq));
            As[kq + 0][row] = v.x;
            As[kq + 1][row] = v.y;
            As[kq + 2][row] = v.z;
            As[kq + 3][row] = v.w;
        }
        if (BLAYOUT == 0) {
#pragma unroll
            for (int jj = 0; jj < 2; ++jj) {
                const int idx = tid + jj * 256;
                const int row = idx >> 2;
                const int kq  = (idx & 3) * 4;
                const float4 v = *(const float4*)(B + (size_t)(n0 + row) * K + (k0 + kq));
                Bs[kq + 0][row] = v.x;
                Bs[kq + 1][row] = v.y;
                Bs[kq + 2][row] = v.z;
                Bs[kq + 3][row] = v.w;
            }
        } else {
#pragma unroll
            for (int jj = 0; jj < 2; ++jj) {
                const int idx = tid + jj * 256;
                const int kr  = idx >> 5;
                const int nc  = (idx & 31) * 4;
                const float4 v = *(const float4*)(B + (size_t)(k0 + kr) * N + (n0 + nc));
                *(float4*)&Bs[kr][nc] = v;
            }
        }
        __syncthreads();
#pragma unroll
        for (int k = 0; k < 16; ++k) {
            const float4 a0 = *(const float4*)&As[k][ty * 4];
            const float4 a1 = *(const float4*)&As[k][64 + ty * 4];
            const float4 b0 = *(const float4*)&Bs[k][tx * 4];
            const float4 b1 = *(const float4*)&Bs[k][64 + tx * 4];
            const float a[8] = {a0.x, a0.y, a0.z, a0.w, a1.x, a1.y, a1.z, a1.w};
            const float b[8] = {b0.x, b0.y, b0.z, b0.w, b1.x, b1.y, b1.z, b1.w};
#pragma unroll
            for (int i = 0; i < 8; ++i)
#pragma unroll
                for (int j = 0; j < 8; ++j) acc[i][j] = fmaf(a[i], b[j], acc[i][j]);
        }
    }

#pragma unroll
    for (int i = 0; i < 8; ++i) {
        const int row = m0 + ((i < 4) ? (ty * 4 + i) : (64 + ty * 4 + (i - 4)));
#pragma unroll
        for (int jb = 0; jb < 2; ++jb) {
            const int col = n0 + jb * 64 + tx * 4;
            const float4 bv = *(const float4*)(bias + col);
            float4 v;
            v.x = acc[i][jb * 4 + 0] + bv.x;
            v.y = acc[i][jb * 4 + 1] + bv.y;
            v.z = acc[i][jb * 4 + 2] + bv.z;
            v.w = acc[i][jb * 4 + 3] + bv.w;
            if constexpr (EPI == 1) {
                v.x = gelu_exact(v.x);
                v.y = gelu_exact(v.y);
                v.z = gelu_exact(v.z);
                v.w = gelu_exact(v.w);
            }
            if constexpr (EPI == 2) {
                const float4 r = *(const float4*)(resg + (size_t)row * N + col);
                v.x += r.x; v.y += r.y; v.z += r.z; v.w += r.w;
            }
            *(float4*)(C + (size_t)row * N + col) = v;
        }
    }
}

// ---------------------------- Flash attention ------------------------------
// One block per (q-tile of 64 rows, b*NH).  Non-causal, scale 1/8.
__global__ __launch_bounds__(256) void attn_kernel(const float* __restrict__ qkv,
                                                   float* __restrict__ o) {
    const int qt = blockIdx.x;   // 0..15
    const int bh = blockIdx.y;   // 0..63
    const int bb = bh >> 4;
    const int hh = bh & 15;
    const int tid = threadIdx.x;
    const int r0 = (tid >> 4) * 4;
    const int c0 = (tid & 15) * 4;

    __shared__ float Qt[64][68];  // [d][r]
    __shared__ float Kt[64][68];  // [d][c]
    __shared__ float Vs[64][68];  // [k][c]
    __shared__ float Ps[64][65];  // [r][k]

    const size_t base = (size_t)bb * Tc * 3072 + hh * 64;

#pragma unroll
    for (int jj = 0; jj < 4; ++jj) {
        const int idx = tid + jj * 256;
        const int rr = idx >> 4;
        const int cc = (idx & 15) * 4;
        const float4 v = *(const float4*)(qkv + base + (size_t)(qt * 64 + rr) * 3072 + cc);
        Qt[cc + 0][rr] = v.x;
        Qt[cc + 1][rr] = v.y;
        Qt[cc + 2][rr] = v.z;
        Qt[cc + 3][rr] = v.w;
    }

    float m[4], l[4], acc[4][4];
#pragma unroll
    for (int i = 0; i < 4; ++i) {
        m[i] = -1e30f;
        l[i] = 0.0f;
#pragma unroll
        for (int j = 0; j < 4; ++j) acc[i][j] = 0.0f;
    }

    for (int kt = 0; kt < 16; ++kt) {
        __syncthreads();  // protect Kt/Vs/Ps from previous iteration's readers
#pragma unroll
        for (int jj = 0; jj < 4; ++jj) {
            const int idx = tid + jj * 256;
            const int rr = idx >> 4;
            const int cc = (idx & 15) * 4;
            const float* kp = qkv + base + (size_t)(kt * 64 + rr) * 3072 + Hc + cc;
            const float4 kv = *(const float4*)kp;
            const float4 vv = *(const float4*)(kp + Hc);
            Kt[cc + 0][rr] = kv.x;
            Kt[cc + 1][rr] = kv.y;
            Kt[cc + 2][rr] = kv.z;
            Kt[cc + 3][rr] = kv.w;
            *(float4*)&Vs[rr][cc] = vv;
        }
        __syncthreads();

        float sv[4][4];
#pragma unroll
        for (int i = 0; i < 4; ++i)
#pragma unroll
            for (int j = 0; j < 4; ++j) sv[i][j] = 0.0f;

#pragma unroll 8
        for (int d = 0; d < 64; ++d) {
            const float4 qv = *(const float4*)&Qt[d][r0];
            const float4 kv = *(const float4*)&Kt[d][c0];
            const float qa[4] = {qv.x, qv.y, qv.z, qv.w};
            const float ka[4] = {kv.x, kv.y, kv.z, kv.w};
#pragma unroll
            for (int i = 0; i < 4; ++i)
#pragma unroll
                for (int j = 0; j < 4; ++j) sv[i][j] = fmaf(qa[i], ka[j], sv[i][j]);
        }

#pragma unroll
        for (int i = 0; i < 4; ++i) {
#pragma unroll
            for (int j = 0; j < 4; ++j) sv[i][j] *= 0.125f;
            float mx = fmaxf(fmaxf(sv[i][0], sv[i][1]), fmaxf(sv[i][2], sv[i][3]));
#pragma unroll
            for (int msk = 1; msk < 16; msk <<= 1) mx = fmaxf(mx, __shfl_xor(mx, msk));
            const float mn = fmaxf(m[i], mx);
            const float sc = expf(m[i] - mn);
            float rs = 0.0f;
#pragma unroll
            for (int j = 0; j < 4; ++j) {
                const float p = expf(sv[i][j] - mn);
                sv[i][j] = p;
                rs += p;
            }
#pragma unroll
            for (int msk = 1; msk < 16; msk <<= 1) rs += __shfl_xor(rs, msk);
            l[i] = l[i] * sc + rs;
            m[i] = mn;
#pragma unroll
            for (int j = 0; j < 4; ++j) acc[i][j] *= sc;
            Ps[r0 + i][c0 + 0] = sv[i][0];
            Ps[r0 + i][c0 + 1] = sv[i][1];
            Ps[r0 + i][c0 + 2] = sv[i][2];
            Ps[r0 + i][c0 + 3] = sv[i][3];
        }
        __syncthreads();

#pragma unroll 4
        for (int k = 0; k < 64; ++k) {
            const float p0 = Ps[r0 + 0][k];
            const float p1 = Ps[r0 + 1][k];
            const float p2 = Ps[r0 + 2][k];
            const float p3 = Ps[r0 + 3][k];
            const float4 vv = *(const float4*)&Vs[k][c0];
            acc[0][0] = fmaf(p0, vv.x, acc[0][0]);
            acc[0][1] = fmaf(p0, vv.y, acc[0][1]);
            acc[0][2] = fmaf(p0, vv.z, acc[0][2]);
            acc[0][3] = fmaf(p0, vv.w, acc[0][3]);
            acc[1][0] = fmaf(p1, vv.x, acc[1][0]);
            acc[1][1] = fmaf(p1, vv.y, acc[1][1]);
            acc[1][2] = fmaf(p1, vv.z, acc[1][2]);
            acc[1][3] = fmaf(p1, vv.w, acc[1][3]);
            acc[2][0] = fmaf(p2, vv.x, acc[2][0]);
            acc[2][1] = fmaf(p2, vv.y, acc[2][1]);
            acc[2][2] = fmaf(p2, vv.z, acc[2][2]);
            acc[2][3] = fmaf(p2, vv.w, acc[2][3]);
            acc[3][0] = fmaf(p3, vv.x, acc[3][0]);
            acc[3][1] = fmaf(p3, vv.y, acc[3][1]);
            acc[3][2] = fmaf(p3, vv.z, acc[3][2]);
            acc[3][3] = fmaf(p3, vv.w, acc[3][3]);
        }
    }

#pragma unroll
    for (int i = 0; i < 4; ++i) {
        const float inv = 1.0f / l[i];
        float4 r;
        r.x = acc[i][0] * inv;
        r.y = acc[i][1] * inv;
        r.z = acc[i][2] * inv;
        r.w = acc[i][3] * inv;
        *(float4*)(o + (size_t)(bb * Tc + qt * 64 + r0 + i) * Hc + hh * 64 + c0) = r;
    }
}

// ---------------------------- MoE gating -----------------------------------
__global__ __launch_bounds__(256) void gate_kernel(const float* __restrict__ h2,
                                                   const float* __restrict__ wg,
                                                   int* __restrict__ eidx,
                                                   float* __restrict__ gvr) {
    const int s = blockIdx.x;
    const int tid = threadIdx.x;
    const float4 hv = ((const float4*)(h2 + (size_t)s * Hc))[tid];
    const float hx[4] = {hv.x, hv.y, hv.z, hv.w};
    float p[8];
#pragma unroll
    for (int e2 = 0; e2 < 8; ++e2) p[e2] = 0.0f;
#pragma unroll
    for (int i = 0; i < 4; ++i) {
        const int k = tid * 4 + i;
        const float4 w0 = *(const float4*)(wg + (size_t)k * 8);
        const float4 w1 = *(const float4*)(wg + (size_t)k * 8 + 4);
        p[0] = fmaf(hx[i], w0.x, p[0]);
        p[1] = fmaf(hx[i], w0.y, p[1]);
        p[2] = fmaf(hx[i], w0.z, p[2]);
        p[3] = fmaf(hx[i], w0.w, p[3]);
        p[4] = fmaf(hx[i], w1.x, p[4]);
        p[5] = fmaf(hx[i], w1.y, p[5]);
        p[6] = fmaf(hx[i], w1.z, p[6]);
        p[7] = fmaf(hx[i], w1.w, p[7]);
    }
#pragma unroll
    for (int e2 = 0; e2 < 8; ++e2)
#pragma unroll
        for (int msk = 1; msk < 64; msk <<= 1) p[e2] += __shfl_xor(p[e2], msk);
    __shared__ float lg[4][8];
    if ((tid & 63) == 0) {
#pragma unroll
        for (int e2 = 0; e2 < 8; ++e2) lg[tid >> 6][e2] = p[e2];
    }
    __syncthreads();
    if (tid == 0) {
        float l[8];
#pragma unroll
        for (int e2 = 0; e2 < 8; ++e2) l[e2] = lg[0][e2] + lg[1][e2] + lg[2][e2] + lg[3][e2];
        int best = 0;
        float bm = l[0];
#pragma unroll
        for (int e2 = 1; e2 < 8; ++e2)
            if (l[e2] > bm) { bm = l[e2]; best = e2; }
        float se = 0.0f;
#pragma unroll
        for (int e2 = 0; e2 < 8; ++e2) se += expf(l[e2] - bm);
        eidx[s] = best;
        gvr[s] = 1.0f / se;  // softmax value at argmax
    }
}

// ---------------------------- MoE routing scan (order-dependent) -----------
__global__ __launch_bounds__(256) void route_kernel(const int* __restrict__ eidx,
                                                    const float* __restrict__ gvr,
                                                    int* __restrict__ posc,
                                                    float* __restrict__ gval,
                                                    int* __restrict__ s2t,
                                                    int* __restrict__ counts) {
    __shared__ int running[8];
    __shared__ unsigned long long wb[8][4];
    const int tid = threadIdx.x;
    const int wave = tid >> 6;
    const int lane = tid & 63;
    if (tid < 8) running[tid] = 0;
    __syncthreads();
    for (int chunk = 0; chunk < Sc / 256; ++chunk) {
        const int s = chunk * 256 + tid;
        const int e = eidx[s];
#pragma unroll
        for (int ex = 0; ex < 8; ++ex) {
            const unsigned long long bl = __ballot(e == ex);
            if (lane == 0) wb[ex][wave] = bl;
        }
        __syncthreads();
        int before = running[e];
#pragma unroll
        for (int w = 0; w < 4; ++w) {
            const unsigned long long bw = wb[e][w];
            if (w < wave) before += __popcll(bw);
            else if (w == wave) before += __popcll(bw & ((1ull << lane) - 1ull));
        }
        const int pos = before;
        const int keep = pos < CAPc;
        posc[s] = keep ? pos : (CAPc - 1);
        gval[s] = keep ? gvr[s] : 0.0f;
        if (keep) s2t[e * CAPc + pos] = s;
        __syncthreads();
        if (tid < 8) {
            int tot = 0;
#pragma unroll
            for (int w = 0; w < 4; ++w) tot += __popcll(wb[tid][w]);
            running[tid] += tot;
        }
        __syncthreads();
    }
    if (tid < 8) counts[tid] = running[tid];
}

// ---------------------------- MoE dispatch ---------------------------------
__global__ __launch_bounds__(256) void dispatch_kernel(const float* __restrict__ h2,
                                                       const int* __restrict__ s2t,
                                                       const int* __restrict__ counts,
                                                       float* __restrict__ disp) {
    const int slot = blockIdx.x;      // e*CAP + c
    const int e = slot >> 9;
    const int c = slot & (CAPc - 1);
    int cnt = counts[e];
    cnt = cnt > CAPc ? CAPc : cnt;
    float4* dst = (float4*)(disp + (size_t)slot * Hc);
    if (c < cnt) {
        const int s = s2t[slot];
        dst[threadIdx.x] = ((const float4*)(h2 + (size_t)s * Hc))[threadIdx.x];
    } else {
        dst[threadIdx.x] = make_float4(0.f, 0.f, 0.f, 0.f);  // NaN-proof unfilled slots
    }
}

// ---------------------------- MoE gather + residual ------------------------
__global__ __launch_bounds__(256) void gather_kernel(const float* __restrict__ x1,
                                                     const float* __restrict__ eout,
                                                     const int* __restrict__ eidx,
                                                     const int* __restrict__ posc,
                                                     const float* __restrict__ gval,
                                                     float* __restrict__ out) {
    const int s = blockIdx.x;
    const float g = gval[s];
    const int slot = eidx[s] * CAPc + posc[s];
    const float4 a = ((const float4*)(x1 + (size_t)s * Hc))[threadIdx.x];
    const float4 b = ((const float4*)(eout + (size_t)slot * Hc))[threadIdx.x];
    float4 r;
    r.x = a.x + b.x * g;
    r.y = a.y + b.y * g;
    r.z = a.z + b.z * g;
    r.w = a.w + b.w * g;
    ((float4*)(out + (size_t)s * Hc))[threadIdx.x] = r;
}

// ---------------------------------------------------------------------------
extern "C" void kernel_launch(void* const* d_in, const int* in_sizes, int n_in,
                              void* d_out, int out_size, void* d_ws, size_t ws_size,
                              hipStream_t stream) {
    const float* x     = (const float*)d_in[0];
    const float* ln1_w = (const float*)d_in[1];
    const float* ln1_b = (const float*)d_in[2];
    const float* in_w  = (const float*)d_in[3];
    const float* in_b  = (const float*)d_in[4];
    const float* out_w = (const float*)d_in[5];
    const float* out_b = (const float*)d_in[6];
    const float* ln2_w = (const float*)d_in[7];
    const float* ln2_b = (const float*)d_in[8];
    const float* wg    = (const float*)d_in[9];
    const float* w1    = (const float*)d_in[10];
    const float* b1    = (const float*)d_in[11];
    const float* w2    = (const float*)d_in[12];
    const float* b2    = (const float*)d_in[13];
    float* out = (float*)d_out;
    float* ws  = (float*)d_ws;

    const size_t SH = (size_t)Sc * Hc;  // 4M floats
    // Buffer plan (96 MB + ~100 KB of d_ws):
    //  buf0 [4M]  : h  (ln1 out)          -> disp (after qkv gemm frees h)
    //  buf1 [16M] : qkv (12M) + attno(4M) -> hmid (after out_proj frees both)
    //  buf3 [4M]  : h2 (ln2 out)          -> eout (after dispatch frees h2)
    //  x1 lives in d_out (overwritten element-wise by the final gather).
    float* buf0 = ws;
    float* buf1 = buf0 + SH;
    float* buf3 = buf1 + 4 * SH;
    float* gvr  = buf3 + SH;
    float* gval = gvr + Sc;
    int* eidx   = (int*)(gval + Sc);
    int* posc   = eidx + Sc;
    int* s2t    = posc + Sc;
    int* counts = s2t + Ec * CAPc;

    float* h     = buf0;
    float* qkv   = buf1;
    float* attno = buf1 + 3 * SH;
    float* x1    = out;   // d_out doubles as the attn-residual buffer
    float* h2    = buf3;
    float* disp  = buf0;
    float* hmid  = buf1;
    float* eout  = buf3;

    // 1. LN1
    ln_kernel<<<Sc, 256, 0, stream>>>(x, ln1_w, ln1_b, h);
    // 2. qkv = h @ in_w^T + in_b              [4096,3072]
    gemm_k<0, 0><<<dim3(3072 / 128, 4096 / 128, 1), 256, 0, stream>>>(
        h, in_w, in_b, nullptr, qkv, Sc, 3 * Hc, Hc, 0, 0, 0, 0);
    // 3. flash attention -> attno             [4096,1024]
    attn_kernel<<<dim3(Tc / 64, Bc * NHc), 256, 0, stream>>>(qkv, attno);
    // 4. x1 = attno @ out_w^T + out_b + x
    gemm_k<0, 2><<<dim3(Hc / 128, 4096 / 128, 1), 256, 0, stream>>>(
        attno, out_w, out_b, x, x1, Sc, Hc, Hc, 0, 0, 0, 0);
    // 5. LN2
    ln_kernel<<<Sc, 256, 0, stream>>>(x1, ln2_w, ln2_b, h2);
    // 6. gating
    gate_kernel<<<Sc, 256, 0, stream>>>(h2, wg, eidx, gvr);
    // 7. order-dependent routing scan (single block)
    route_kernel<<<1, 256, 0, stream>>>(eidx, gvr, posc, gval, s2t, counts);
    // 8. dispatch into [E,CAP,H] (zero-fills unused slots)
    dispatch_kernel<<<Ec * CAPc, 256, 0, stream>>>(h2, s2t, counts, disp);
    // 9. hmid = gelu(disp @ w1 + b1)          [E,512,4096]
    gemm_k<1, 1><<<dim3(FFc / 128, CAPc / 128, Ec), 256, 0, stream>>>(
        disp, w1, b1, nullptr, hmid, CAPc, FFc, Hc,
        (long long)CAPc * Hc, (long long)Hc * FFc, (long long)CAPc * FFc, FFc);
    // 10. eout = hmid @ w2 + b2               [E,512,1024]
    gemm_k<1, 0><<<dim3(Hc / 128, CAPc / 128, Ec), 256, 0, stream>>>(
        hmid, w2, b2, nullptr, eout, CAPc, Hc, FFc,
        (long long)CAPc * FFc, (long long)FFc * Hc, (long long)CAPc * Hc, Hc);
    // 11. out = x1 + eout[route] * gval
    gather_kernel<<<Sc, 256, 0, stream>>>(x1, eout, eidx, posc, gval, out);
}

// Round 3
// 1036.975 us; speedup vs baseline: 1.8579x; 1.8579x over previous
//
#include <hip/hip_runtime.h>
#include <hip/hip_bf16.h>

// ---------------------------------------------------------------------------
// TransformerBlock: LN1 -> attn -> +res -> LN2 -> MoE(top1,cap) -> +res
// B=4 T=1024 H=1024 NH=16 DH=64 E=8 CAP=512 S=4096 FF=4096
// Round 3: all four GEMMs -> bf16 MFMA (16x16x32), 128x128x32 tiles, 4 waves,
// reg-staged LDS (+pad), fp32 weights converted to bf16 in-register during
// staging. Activations between GEMMs carried as bf16. Attention still fp32.
// Workspace: 72 MB (< proven 96 MB).
// ---------------------------------------------------------------------------

#define Bc   4
#define Tc   1024
#define Hc   1024
#define NHc  16
#define DHc  64
#define Ec   8
#define CAPc 512
#define Sc   4096
#define FFc  4096

typedef __attribute__((ext_vector_type(8))) short bf16x8;
typedef __attribute__((ext_vector_type(4))) float f32x4;

#define LDP 40   // LDS row stride in bf16 elems (32 data + 8 pad -> 80B rows)

__device__ __forceinline__ float gelu_exact(float x) {
    return 0.5f * x * (1.0f + erff(x * 0.70710678118654752440f));
}

__device__ __forceinline__ ushort f2bf(float f) {
    union { __hip_bfloat16 h; ushort u; } c;
    c.h = __float2bfloat16(f);
    return c.u;
}

__device__ __forceinline__ ushort4 pack4(float a, float b, float c, float d) {
    ushort4 r;
    r.x = f2bf(a); r.y = f2bf(b); r.z = f2bf(c); r.w = f2bf(d);
    return r;
}

// ---------------------------- LayerNorm ------------------------------------
// OUTBF=1: write bf16 (ushort), OUTBF=0: write fp32.
template <int OUTBF>
__global__ __launch_bounds__(256) void ln_kernel(const float* __restrict__ x,
                                                 const float* __restrict__ w,
                                                 const float* __restrict__ b,
                                                 void* __restrict__ o) {
    const int row = blockIdx.x;
    const int tid = threadIdx.x;
    const float4 v = ((const float4*)(x + (size_t)row * Hc))[tid];
    float s = v.x + v.y + v.z + v.w;
    float q = v.x * v.x + v.y * v.y + v.z * v.z + v.w * v.w;
#pragma unroll
    for (int m = 1; m < 64; m <<= 1) {
        s += __shfl_xor(s, m);
        q += __shfl_xor(q, m);
    }
    __shared__ float ss[4], qq[4];
    if ((tid & 63) == 0) { ss[tid >> 6] = s; qq[tid >> 6] = q; }
    __syncthreads();
    s = ss[0] + ss[1] + ss[2] + ss[3];
    q = qq[0] + qq[1] + qq[2] + qq[3];
    const float mean = s * (1.0f / Hc);
    const float var  = q * (1.0f / Hc) - mean * mean;
    const float inv  = 1.0f / sqrtf(var + 1e-5f);
    const float4 wv = ((const float4*)w)[tid];
    const float4 bv = ((const float4*)b)[tid];
    float4 r;
    r.x = (v.x - mean) * inv * wv.x + bv.x;
    r.y = (v.y - mean) * inv * wv.y + bv.y;
    r.z = (v.z - mean) * inv * wv.z + bv.z;
    r.w = (v.w - mean) * inv * wv.w + bv.w;
    if (OUTBF) {
        ((ushort4*)((ushort*)o + (size_t)row * Hc))[tid] = pack4(r.x, r.y, r.z, r.w);
    } else {
        ((float4*)((float*)o + (size_t)row * Hc))[tid] = r;
    }
}

// ---------------------------- bf16 MFMA GEMM --------------------------------
// C[M,N] = A[M,K](bf16) @ B(fp32, cvt->bf16 in staging) + bias.
// BLAYOUT 0: B is [N,K] (K-contig).  BLAYOUT 1: B is [K,N] (N-contig).
// EPI 0: +bias.  1: gelu(+bias).  2: +bias +res.
// OUTBF 1: bf16 output.  Batched over blockIdx.z with element strides.
// 128x128 tile, BK=32, 4 waves (2x2), each wave 64x64 = 4x4 frags of 16x16.
template <int BLAYOUT, int EPI, int OUTBF>
__global__ __launch_bounds__(256) void mgemm(const ushort* __restrict__ Ag,
                                             const float* __restrict__ Bg,
                                             const float* __restrict__ biasg,
                                             const float* __restrict__ resg,
                                             void* __restrict__ Cg,
                                             int M, int N, int K,
                                             long long sA, long long sB,
                                             long long sC, long long sBias) {
    const int e = blockIdx.z;
    const ushort* A    = Ag + (size_t)e * sA;
    const float*  B    = Bg + (size_t)e * sB;
    const float*  bias = biasg + (size_t)e * sBias;

    const int m0 = blockIdx.y * 128;
    const int n0 = blockIdx.x * 128;
    const int tid  = threadIdx.x;
    const int lane = tid & 63;
    const int wid  = tid >> 6;
    const int wm   = wid >> 1;       // wave row (0..1)
    const int wn   = wid & 1;        // wave col (0..1)
    const int lg   = lane >> 4;      // k-group 0..3
    const int lr   = lane & 15;      // row/col within 16

    __shared__ ushort As[128 * LDP];
    __shared__ ushort Bs[128 * LDP];

    f32x4 acc[4][4];
#pragma unroll
    for (int i = 0; i < 4; ++i)
#pragma unroll
        for (int j = 0; j < 4; ++j) acc[i][j] = (f32x4){0.f, 0.f, 0.f, 0.f};

    // A staging: 128x32 bf16 tile = 512 chunks of 16B; thread handles chunks
    // tid and tid+256. chunk c -> row c>>2, sub c&3.
    const int asub = tid & 3;
    // B staging: 128 rows (n) x 32 k; thread handles row tid>>1, k-half (tid&1)*16.
    const int bn  = tid >> 1;
    const int bkh = (tid & 1) * 16;

    for (int k0 = 0; k0 < K; k0 += 32) {
        __syncthreads();
        // ---- stage A (bf16 -> bf16, 16B vector copies) ----
#pragma unroll
        for (int j = 0; j < 2; ++j) {
            const int row = (tid >> 2) + j * 64;
            const uint4 v = *(const uint4*)(A + (size_t)(m0 + row) * K + k0 + asub * 8);
            *(uint4*)&As[row * LDP + asub * 8] = v;
        }
        // ---- stage B (fp32 -> bf16) ----
        if (BLAYOUT == 0) {
#pragma unroll
            for (int q = 0; q < 4; ++q) {
                const float4 v = *(const float4*)(B + (size_t)(n0 + bn) * K + k0 + bkh + q * 4);
                *(ushort4*)&Bs[bn * LDP + bkh + q * 4] = pack4(v.x, v.y, v.z, v.w);
            }
        } else {
            float vv[16];
#pragma unroll
            for (int kk = 0; kk < 16; ++kk)
                vv[kk] = B[(size_t)(k0 + bkh + kk) * N + n0 + bn];
#pragma unroll
            for (int q = 0; q < 4; ++q)
                *(ushort4*)&Bs[bn * LDP + bkh + q * 4] =
                    pack4(vv[q * 4], vv[q * 4 + 1], vv[q * 4 + 2], vv[q * 4 + 3]);
        }
        __syncthreads();

        // ---- fragments + MFMA ----
        bf16x8 af[4], bfr[4];
#pragma unroll
        for (int t = 0; t < 4; ++t) {
            af[t]  = *(const bf16x8*)&As[(wm * 64 + t * 16 + lr) * LDP + lg * 8];
            bfr[t] = *(const bf16x8*)&Bs[(wn * 64 + t * 16 + lr) * LDP + lg * 8];
        }
#pragma unroll
        for (int mt = 0; mt < 4; ++mt)
#pragma unroll
            for (int nt = 0; nt < 4; ++nt)
                acc[mt][nt] = __builtin_amdgcn_mfma_f32_16x16x32_bf16(
                    af[mt], bfr[nt], acc[mt][nt], 0, 0, 0);
    }

    // ---- epilogue: C[m][n], m = lg*4+r within frag, n = lr ----
#pragma unroll
    for (int nt = 0; nt < 4; ++nt) {
        const int n = n0 + wn * 64 + nt * 16 + lr;
        const float bv = bias[n];
#pragma unroll
        for (int mt = 0; mt < 4; ++mt) {
#pragma unroll
            for (int r = 0; r < 4; ++r) {
                const int m = m0 + wm * 64 + mt * 16 + lg * 4 + r;
                float v = acc[mt][nt][r] + bv;
                if constexpr (EPI == 1) v = gelu_exact(v);
                if constexpr (EPI == 2) v += resg[(size_t)m * N + n];
                if constexpr (OUTBF) {
                    ((ushort*)Cg)[(size_t)e * sC + (size_t)m * N + n] = f2bf(v);
                } else {
                    ((float*)Cg)[(size_t)e * sC + (size_t)m * N + n] = v;
                }
            }
        }
    }
}

// ---------------------------- Flash attention (fp32) ------------------------
// One block per (q-tile of 64 rows, b*NH). Non-causal, scale 1/8. bf16 output.
__global__ __launch_bounds__(256) void attn_kernel(const float* __restrict__ qkv,
                                                   ushort* __restrict__ o) {
    const int qt = blockIdx.x;   // 0..15
    const int bh = blockIdx.y;   // 0..63
    const int bb = bh >> 4;
    const int hh = bh & 15;
    const int tid = threadIdx.x;
    const int r0 = (tid >> 4) * 4;
    const int c0 = (tid & 15) * 4;

    __shared__ float Qt[64][68];  // [d][r]
    __shared__ float Kt[64][68];  // [d][c]
    __shared__ float Vs[64][68];  // [k][c]
    __shared__ float Ps[64][65];  // [r][k]

    const size_t base = (size_t)bb * Tc * 3072 + hh * 64;

#pragma unroll
    for (int jj = 0; jj < 4; ++jj) {
        const int idx = tid + jj * 256;
        const int rr = idx >> 4;
        const int cc = (idx & 15) * 4;
        const float4 v = *(const float4*)(qkv + base + (size_t)(qt * 64 + rr) * 3072 + cc);
        Qt[cc + 0][rr] = v.x;
        Qt[cc + 1][rr] = v.y;
        Qt[cc + 2][rr] = v.z;
        Qt[cc + 3][rr] = v.w;
    }

    float m[4], l[4], acc[4][4];
#pragma unroll
    for (int i = 0; i < 4; ++i) {
        m[i] = -1e30f;
        l[i] = 0.0f;
#pragma unroll
        for (int j = 0; j < 4; ++j) acc[i][j] = 0.0f;
    }

    for (int kt = 0; kt < 16; ++kt) {
        __syncthreads();
#pragma unroll
        for (int jj = 0; jj < 4; ++jj) {
            const int idx = tid + jj * 256;
            const int rr = idx >> 4;
            const int cc = (idx & 15) * 4;
            const float* kp = qkv + base + (size_t)(kt * 64 + rr) * 3072 + Hc + cc;
            const float4 kv = *(const float4*)kp;
            const float4 vv = *(const float4*)(kp + Hc);
            Kt[cc + 0][rr] = kv.x;
            Kt[cc + 1][rr] = kv.y;
            Kt[cc + 2][rr] = kv.z;
            Kt[cc + 3][rr] = kv.w;
            *(float4*)&Vs[rr][cc] = vv;
        }
        __syncthreads();

        float sv[4][4];
#pragma unroll
        for (int i = 0; i < 4; ++i)
#pragma unroll
            for (int j = 0; j < 4; ++j) sv[i][j] = 0.0f;

#pragma unroll 8
        for (int d = 0; d < 64; ++d) {
            const float4 qv = *(const float4*)&Qt[d][r0];
            const float4 kv = *(const float4*)&Kt[d][c0];
            const float qa[4] = {qv.x, qv.y, qv.z, qv.w};
            const float ka[4] = {kv.x, kv.y, kv.z, kv.w};
#pragma unroll
            for (int i = 0; i < 4; ++i)
#pragma unroll
                for (int j = 0; j < 4; ++j) sv[i][j] = fmaf(qa[i], ka[j], sv[i][j]);
        }

#pragma unroll
        for (int i = 0; i < 4; ++i) {
#pragma unroll
            for (int j = 0; j < 4; ++j) sv[i][j] *= 0.125f;
            float mx = fmaxf(fmaxf(sv[i][0], sv[i][1]), fmaxf(sv[i][2], sv[i][3]));
#pragma unroll
            for (int msk = 1; msk < 16; msk <<= 1) mx = fmaxf(mx, __shfl_xor(mx, msk));
            const float mn = fmaxf(m[i], mx);
            const float sc = expf(m[i] - mn);
            float rs = 0.0f;
#pragma unroll
            for (int j = 0; j < 4; ++j) {
                const float p = expf(sv[i][j] - mn);
                sv[i][j] = p;
                rs += p;
            }
#pragma unroll
            for (int msk = 1; msk < 16; msk <<= 1) rs += __shfl_xor(rs, msk);
            l[i] = l[i] * sc + rs;
            m[i] = mn;
#pragma unroll
            for (int j = 0; j < 4; ++j) acc[i][j] *= sc;
            Ps[r0 + i][c0 + 0] = sv[i][0];
            Ps[r0 + i][c0 + 1] = sv[i][1];
            Ps[r0 + i][c0 + 2] = sv[i][2];
            Ps[r0 + i][c0 + 3] = sv[i][3];
        }
        __syncthreads();

#pragma unroll 4
        for (int k = 0; k < 64; ++k) {
            const float p0 = Ps[r0 + 0][k];
            const float p1 = Ps[r0 + 1][k];
            const float p2 = Ps[r0 + 2][k];
            const float p3 = Ps[r0 + 3][k];
            const float4 vv = *(const float4*)&Vs[k][c0];
            acc[0][0] = fmaf(p0, vv.x, acc[0][0]);
            acc[0][1] = fmaf(p0, vv.y, acc[0][1]);
            acc[0][2] = fmaf(p0, vv.z, acc[0][2]);
            acc[0][3] = fmaf(p0, vv.w, acc[0][3]);
            acc[1][0] = fmaf(p1, vv.x, acc[1][0]);
            acc[1][1] = fmaf(p1, vv.y, acc[1][1]);
            acc[1][2] = fmaf(p1, vv.z, acc[1][2]);
            acc[1][3] = fmaf(p1, vv.w, acc[1][3]);
            acc[2][0] = fmaf(p2, vv.x, acc[2][0]);
            acc[2][1] = fmaf(p2, vv.y, acc[2][1]);
            acc[2][2] = fmaf(p2, vv.z, acc[2][2]);
            acc[2][3] = fmaf(p2, vv.w, acc[2][3]);
            acc[3][0] = fmaf(p3, vv.x, acc[3][0]);
            acc[3][1] = fmaf(p3, vv.y, acc[3][1]);
            acc[3][2] = fmaf(p3, vv.z, acc[3][2]);
            acc[3][3] = fmaf(p3, vv.w, acc[3][3]);
        }
    }

#pragma unroll
    for (int i = 0; i < 4; ++i) {
        const float inv = 1.0f / l[i];
        *(ushort4*)(o + (size_t)(bb * Tc + qt * 64 + r0 + i) * Hc + hh * 64 + c0) =
            pack4(acc[i][0] * inv, acc[i][1] * inv, acc[i][2] * inv, acc[i][3] * inv);
    }
}

// ---------------------------- MoE gating -----------------------------------
__global__ __launch_bounds__(256) void gate_kernel(const float* __restrict__ h2,
                                                   const float* __restrict__ wg,
                                                   int* __restrict__ eidx,
                                                   float* __restrict__ gvr) {
    const int s = blockIdx.x;
    const int tid = threadIdx.x;
    const float4 hv = ((const float4*)(h2 + (size_t)s * Hc))[tid];
    const float hx[4] = {hv.x, hv.y, hv.z, hv.w};
    float p[8];
#pragma unroll
    for (int e2 = 0; e2 < 8; ++e2) p[e2] = 0.0f;
#pragma unroll
    for (int i = 0; i < 4; ++i) {
        const int k = tid * 4 + i;
        const float4 w0 = *(const float4*)(wg + (size_t)k * 8);
        const float4 w1 = *(const float4*)(wg + (size_t)k * 8 + 4);
        p[0] = fmaf(hx[i], w0.x, p[0]);
        p[1] = fmaf(hx[i], w0.y, p[1]);
        p[2] = fmaf(hx[i], w0.z, p[2]);
        p[3] = fmaf(hx[i], w0.w, p[3]);
        p[4] = fmaf(hx[i], w1.x, p[4]);
        p[5] = fmaf(hx[i], w1.y, p[5]);
        p[6] = fmaf(hx[i], w1.z, p[6]);
        p[7] = fmaf(hx[i], w1.w, p[7]);
    }
#pragma unroll
    for (int e2 = 0; e2 < 8; ++e2)
#pragma unroll
        for (int msk = 1; msk < 64; msk <<= 1) p[e2] += __shfl_xor(p[e2], msk);
    __shared__ float lg[4][8];
    if ((tid & 63) == 0) {
#pragma unroll
        for (int e2 = 0; e2 < 8; ++e2) lg[tid >> 6][e2] = p[e2];
    }
    __syncthreads();
    if (tid == 0) {
        float l[8];
#pragma unroll
        for (int e2 = 0; e2 < 8; ++e2) l[e2] = lg[0][e2] + lg[1][e2] + lg[2][e2] + lg[3][e2];
        int best = 0;
        float bm = l[0];
#pragma unroll
        for (int e2 = 1; e2 < 8; ++e2)
            if (l[e2] > bm) { bm = l[e2]; best = e2; }
        float se = 0.0f;
#pragma unroll
        for (int e2 = 0; e2 < 8; ++e2) se += expf(l[e2] - bm);
        eidx[s] = best;
        gvr[s] = 1.0f / se;  // softmax value at argmax
    }
}

// ---------------------------- MoE routing scan (order-dependent) -----------
__global__ __launch_bounds__(256) void route_kernel(const int* __restrict__ eidx,
                                                    const float* __restrict__ gvr,
                                                    int* __restrict__ posc,
                                                    float* __restrict__ gval,
                                                    int* __restrict__ s2t,
                                                    int* __restrict__ counts) {
    __shared__ int running[8];
    __shared__ unsigned long long wb[8][4];
    const int tid = threadIdx.x;
    const int wave = tid >> 6;
    const int lane = tid & 63;
    if (tid < 8) running[tid] = 0;
    __syncthreads();
    for (int chunk = 0; chunk < Sc / 256; ++chunk) {
        const int s = chunk * 256 + tid;
        const int e = eidx[s];
#pragma unroll
        for (int ex = 0; ex < 8; ++ex) {
            const unsigned long long bl = __ballot(e == ex);
            if (lane == 0) wb[ex][wave] = bl;
        }
        __syncthreads();
        int before = running[e];
#pragma unroll
        for (int w = 0; w < 4; ++w) {
            const unsigned long long bw = wb[e][w];
            if (w < wave) before += __popcll(bw);
            else if (w == wave) before += __popcll(bw & ((1ull << lane) - 1ull));
        }
        const int pos = before;
        const int keep = pos < CAPc;
        posc[s] = keep ? pos : (CAPc - 1);
        gval[s] = keep ? gvr[s] : 0.0f;
        if (keep) s2t[e * CAPc + pos] = s;
        __syncthreads();
        if (tid < 8) {
            int tot = 0;
#pragma unroll
            for (int w = 0; w < 4; ++w) tot += __popcll(wb[tid][w]);
            running[tid] += tot;
        }
        __syncthreads();
    }
    if (tid < 8) counts[tid] = running[tid];
}

// ---------------------------- MoE dispatch (fp32 -> bf16) -------------------
__global__ __launch_bounds__(256) void dispatch_kernel(const float* __restrict__ h2,
                                                       const int* __restrict__ s2t,
                                                       const int* __restrict__ counts,
                                                       ushort* __restrict__ disp) {
    const int slot = blockIdx.x;      // e*CAP + c
    const int e = slot >> 9;
    const int c = slot & (CAPc - 1);
    int cnt = counts[e];
    cnt = cnt > CAPc ? CAPc : cnt;
    ushort4* dst = (ushort4*)(disp + (size_t)slot * Hc);
    if (c < cnt) {
        const int s = s2t[slot];
        const float4 v = ((const float4*)(h2 + (size_t)s * Hc))[threadIdx.x];
        dst[threadIdx.x] = pack4(v.x, v.y, v.z, v.w);
    } else {
        dst[threadIdx.x] = make_ushort4(0, 0, 0, 0);  // bf16 zero = 0x0000
    }
}

// ---------------------------- MoE gather + residual ------------------------
__global__ __launch_bounds__(256) void gather_kernel(const float* __restrict__ x1,
                                                     const float* __restrict__ eout,
                                                     const int* __restrict__ eidx,
                                                     const int* __restrict__ posc,
                                                     const float* __restrict__ gval,
                                                     float* __restrict__ out) {
    const int s = blockIdx.x;
    const float g = gval[s];
    const int slot = eidx[s] * CAPc + posc[s];
    const float4 a = ((const float4*)(x1 + (size_t)s * Hc))[threadIdx.x];
    const float4 b = ((const float4*)(eout + (size_t)slot * Hc))[threadIdx.x];
    float4 r;
    r.x = a.x + b.x * g;
    r.y = a.y + b.y * g;
    r.z = a.z + b.z * g;
    r.w = a.w + b.w * g;
    ((float4*)(out + (size_t)s * Hc))[threadIdx.x] = r;
}

// ---------------------------------------------------------------------------
extern "C" void kernel_launch(void* const* d_in, const int* in_sizes, int n_in,
                              void* d_out, int out_size, void* d_ws, size_t ws_size,
                              hipStream_t stream) {
    const float* x     = (const float*)d_in[0];
    const float* ln1_w = (const float*)d_in[1];
    const float* ln1_b = (const float*)d_in[2];
    const float* in_w  = (const float*)d_in[3];
    const float* in_b  = (const float*)d_in[4];
    const float* out_w = (const float*)d_in[5];
    const float* out_b = (const float*)d_in[6];
    const float* ln2_w = (const float*)d_in[7];
    const float* ln2_b = (const float*)d_in[8];
    const float* wg    = (const float*)d_in[9];
    const float* w1    = (const float*)d_in[10];
    const float* b1    = (const float*)d_in[11];
    const float* w2    = (const float*)d_in[12];
    const float* b2    = (const float*)d_in[13];
    float* out = (float*)d_out;
    float* ws  = (float*)d_ws;

    const size_t SH = (size_t)Sc * Hc;  // 4M elems
    // Workspace (72 MB):
    //  region0 [12M f32 = 48MB]: qkv fp32        -> hmid bf16 (16M u16 = 32MB)
    //  region1 [ 2M f32 =  8MB]: h/attno/disp bf16 (4M u16, sequential reuse)
    //  region2 [ 4M f32 = 16MB]: h2 fp32         -> eout fp32
    //  x1 lives in d_out (overwritten element-wise by the final gather).
    float*  qkv_f  = ws;                       // 12M floats
    ushort* hmid_u = (ushort*)ws;              // 16M ushorts (same region)
    float*  r1     = ws + 3 * SH;
    ushort* hA     = (ushort*)r1;              // 4M ushorts: h -> attno -> disp
    float*  r2     = r1 + SH / 2;
    float*  h2     = r2;                       // 4M floats
    float*  eout   = r2;                       // reuse after dispatch
    float*  smallf = r2 + SH;
    float* gvr  = smallf;
    float* gval = gvr + Sc;
    int* eidx   = (int*)(gval + Sc);
    int* posc   = eidx + Sc;
    int* s2t    = posc + Sc;
    int* counts = s2t + Ec * CAPc;

    float* x1 = out;   // d_out doubles as the attn-residual buffer

    // 1. LN1 -> h (bf16)
    ln_kernel<1><<<Sc, 256, 0, stream>>>(x, ln1_w, ln1_b, hA);
    // 2. qkv = h @ in_w^T + in_b              [4096,3072] fp32 out
    mgemm<0, 0, 0><<<dim3(24, 32, 1), 256, 0, stream>>>(
        hA, in_w, in_b, nullptr, qkv_f, Sc, 3 * Hc, Hc, 0, 0, 0, 0);
    // 3. flash attention -> attno (bf16)
    attn_kernel<<<dim3(Tc / 64, Bc * NHc), 256, 0, stream>>>(qkv_f, hA);
    // 4. x1 = attno @ out_w^T + out_b + x     [4096,1024] fp32 out (d_out)
    mgemm<0, 2, 0><<<dim3(8, 32, 1), 256, 0, stream>>>(
        hA, out_w, out_b, x, x1, Sc, Hc, Hc, 0, 0, 0, 0);
    // 5. LN2 -> h2 (fp32)
    ln_kernel<0><<<Sc, 256, 0, stream>>>(x1, ln2_w, ln2_b, h2);
    // 6. gating
    gate_kernel<<<Sc, 256, 0, stream>>>(h2, wg, eidx, gvr);
    // 7. order-dependent routing scan (single block)
    route_kernel<<<1, 256, 0, stream>>>(eidx, gvr, posc, gval, s2t, counts);
    // 8. dispatch into [E,CAP,H] bf16 (zero-fills unused slots)
    dispatch_kernel<<<Ec * CAPc, 256, 0, stream>>>(h2, s2t, counts, hA);
    // 9. hmid = gelu(disp @ w1 + b1)          [E,512,4096] bf16 out
    mgemm<1, 1, 1><<<dim3(32, 4, Ec), 256, 0, stream>>>(
        hA, w1, b1, nullptr, hmid_u, CAPc, FFc, Hc,
        (long long)CAPc * Hc, (long long)Hc * FFc, (long long)CAPc * FFc, FFc);
    // 10. eout = hmid @ w2 + b2               [E,512,1024] fp32 out
    mgemm<1, 0, 0><<<dim3(8, 4, Ec), 256, 0, stream>>>(
        hmid_u, w2, b2, nullptr, eout, CAPc, Hc, FFc,
        (long long)CAPc * FFc, (long long)FFc * Hc, (long long)CAPc * Hc, Hc);
    // 11. out = x1 + eout[route] * gval
    gather_kernel<<<Sc, 256, 0, stream>>>(x1, eout, eidx, posc, gval, out);
}

// Round 4
// 839.529 us; speedup vs baseline: 2.2948x; 1.2352x over previous
//
#include <hip/hip_runtime.h>
#include <hip/hip_bf16.h>

// ---------------------------------------------------------------------------
// TransformerBlock: LN1 -> attn -> +res -> LN2 -> MoE(top1,cap) -> +res
// B=4 T=1024 H=1024 NH=16 DH=64 E=8 CAP=512 S=4096 FF=4096
// Round 4: attention -> bf16 MFMA flash (16x16x32), qkv carried as bf16.
// GEMMs unchanged from round 3 (bf16 MFMA, 128x128x32, 4 waves).
// ---------------------------------------------------------------------------

#define Bc   4
#define Tc   1024
#define Hc   1024
#define NHc  16
#define DHc  64
#define Ec   8
#define CAPc 512
#define Sc   4096
#define FFc  4096

typedef __attribute__((ext_vector_type(8))) short bf16x8;
typedef __attribute__((ext_vector_type(4))) float f32x4;

#define LDP 40   // GEMM LDS row stride in bf16 elems

__device__ __forceinline__ float gelu_exact(float x) {
    return 0.5f * x * (1.0f + erff(x * 0.70710678118654752440f));
}

__device__ __forceinline__ ushort f2bf(float f) {
    union { __hip_bfloat16 h; ushort u; } c;
    c.h = __float2bfloat16(f);
    return c.u;
}

__device__ __forceinline__ ushort4 pack4(float a, float b, float c, float d) {
    ushort4 r;
    r.x = f2bf(a); r.y = f2bf(b); r.z = f2bf(c); r.w = f2bf(d);
    return r;
}

// ---------------------------- LayerNorm ------------------------------------
template <int OUTBF>
__global__ __launch_bounds__(256) void ln_kernel(const float* __restrict__ x,
                                                 const float* __restrict__ w,
                                                 const float* __restrict__ b,
                                                 void* __restrict__ o) {
    const int row = blockIdx.x;
    const int tid = threadIdx.x;
    const float4 v = ((const float4*)(x + (size_t)row * Hc))[tid];
    float s = v.x + v.y + v.z + v.w;
    float q = v.x * v.x + v.y * v.y + v.z * v.z + v.w * v.w;
#pragma unroll
    for (int m = 1; m < 64; m <<= 1) {
        s += __shfl_xor(s, m);
        q += __shfl_xor(q, m);
    }
    __shared__ float ss[4], qq[4];
    if ((tid & 63) == 0) { ss[tid >> 6] = s; qq[tid >> 6] = q; }
    __syncthreads();
    s = ss[0] + ss[1] + ss[2] + ss[3];
    q = qq[0] + qq[1] + qq[2] + qq[3];
    const float mean = s * (1.0f / Hc);
    const float var  = q * (1.0f / Hc) - mean * mean;
    const float inv  = 1.0f / sqrtf(var + 1e-5f);
    const float4 wv = ((const float4*)w)[tid];
    const float4 bv = ((const float4*)b)[tid];
    float4 r;
    r.x = (v.x - mean) * inv * wv.x + bv.x;
    r.y = (v.y - mean) * inv * wv.y + bv.y;
    r.z = (v.z - mean) * inv * wv.z + bv.z;
    r.w = (v.w - mean) * inv * wv.w + bv.w;
    if (OUTBF) {
        ((ushort4*)((ushort*)o + (size_t)row * Hc))[tid] = pack4(r.x, r.y, r.z, r.w);
    } else {
        ((float4*)((float*)o + (size_t)row * Hc))[tid] = r;
    }
}

// ---------------------------- bf16 MFMA GEMM --------------------------------
// C[M,N] = A[M,K](bf16) @ B(fp32 -> bf16 staged) + bias.
// BLAYOUT 0: B is [N,K].  1: B is [K,N].  EPI 0:+bias 1:gelu 2:+bias+res.
// OUTBF 1: bf16 out.  128x128 tile, BK=32, 4 waves (2x2), 64x64 per wave.
template <int BLAYOUT, int EPI, int OUTBF>
__global__ __launch_bounds__(256) void mgemm(const ushort* __restrict__ Ag,
                                             const float* __restrict__ Bg,
                                             const float* __restrict__ biasg,
                                             const float* __restrict__ resg,
                                             void* __restrict__ Cg,
                                             int M, int N, int K,
                                             long long sA, long long sB,
                                             long long sC, long long sBias) {
    const int e = blockIdx.z;
    const ushort* A    = Ag + (size_t)e * sA;
    const float*  B    = Bg + (size_t)e * sB;
    const float*  bias = biasg + (size_t)e * sBias;

    const int m0 = blockIdx.y * 128;
    const int n0 = blockIdx.x * 128;
    const int tid  = threadIdx.x;
    const int lane = tid & 63;
    const int wid  = tid >> 6;
    const int wm   = wid >> 1;
    const int wn   = wid & 1;
    const int lg   = lane >> 4;
    const int lr   = lane & 15;

    __shared__ ushort As[128 * LDP];
    __shared__ ushort Bs[128 * LDP];

    f32x4 acc[4][4];
#pragma unroll
    for (int i = 0; i < 4; ++i)
#pragma unroll
        for (int j = 0; j < 4; ++j) acc[i][j] = (f32x4){0.f, 0.f, 0.f, 0.f};

    const int asub = tid & 3;
    const int bn  = tid >> 1;
    const int bkh = (tid & 1) * 16;

    for (int k0 = 0; k0 < K; k0 += 32) {
        __syncthreads();
#pragma unroll
        for (int j = 0; j < 2; ++j) {
            const int row = (tid >> 2) + j * 64;
            const uint4 v = *(const uint4*)(A + (size_t)(m0 + row) * K + k0 + asub * 8);
            *(uint4*)&As[row * LDP + asub * 8] = v;
        }
        if (BLAYOUT == 0) {
#pragma unroll
            for (int q = 0; q < 4; ++q) {
                const float4 v = *(const float4*)(B + (size_t)(n0 + bn) * K + k0 + bkh + q * 4);
                *(ushort4*)&Bs[bn * LDP + bkh + q * 4] = pack4(v.x, v.y, v.z, v.w);
            }
        } else {
            float vv[16];
#pragma unroll
            for (int kk = 0; kk < 16; ++kk)
                vv[kk] = B[(size_t)(k0 + bkh + kk) * N + n0 + bn];
#pragma unroll
            for (int q = 0; q < 4; ++q)
                *(ushort4*)&Bs[bn * LDP + bkh + q * 4] =
                    pack4(vv[q * 4], vv[q * 4 + 1], vv[q * 4 + 2], vv[q * 4 + 3]);
        }
        __syncthreads();

        bf16x8 af[4], bfr[4];
#pragma unroll
        for (int t = 0; t < 4; ++t) {
            af[t]  = *(const bf16x8*)&As[(wm * 64 + t * 16 + lr) * LDP + lg * 8];
            bfr[t] = *(const bf16x8*)&Bs[(wn * 64 + t * 16 + lr) * LDP + lg * 8];
        }
#pragma unroll
        for (int mt = 0; mt < 4; ++mt)
#pragma unroll
            for (int nt = 0; nt < 4; ++nt)
                acc[mt][nt] = __builtin_amdgcn_mfma_f32_16x16x32_bf16(
                    af[mt], bfr[nt], acc[mt][nt], 0, 0, 0);
    }

#pragma unroll
    for (int nt = 0; nt < 4; ++nt) {
        const int n = n0 + wn * 64 + nt * 16 + lr;
        const float bv = bias[n];
#pragma unroll
        for (int mt = 0; mt < 4; ++mt) {
#pragma unroll
            for (int r = 0; r < 4; ++r) {
                const int m = m0 + wm * 64 + mt * 16 + lg * 4 + r;
                float v = acc[mt][nt][r] + bv;
                if constexpr (EPI == 1) v = gelu_exact(v);
                if constexpr (EPI == 2) v += resg[(size_t)m * N + n];
                if constexpr (OUTBF) {
                    ((ushort*)Cg)[(size_t)e * sC + (size_t)m * N + n] = f2bf(v);
                } else {
                    ((float*)Cg)[(size_t)e * sC + (size_t)m * N + n] = v;
                }
            }
        }
    }
}

// ---------------------------- bf16 MFMA flash attention ---------------------
// qkv bf16 [S][3H].  Block = (64-row q-tile, b*NH head).  4 waves, wave owns
// 16 q-rows.  Per 64-key tile: K [key][d] LDS (B-op reads d-contig), V^T
// [d][key] LDS (B-op reads key-contig), P [q][key] LDS bf16 (A-op, wave-
// private rows).  Online softmax in fp32.  Out bf16.
__global__ __launch_bounds__(256) void mattn(const ushort* __restrict__ qkv,
                                             ushort* __restrict__ o) {
    const int qt = blockIdx.x;   // 0..15
    const int bh = blockIdx.y;   // 0..63
    const int bb = bh >> 4;
    const int hh = bh & 15;
    const int tid  = threadIdx.x;
    const int lane = tid & 63;
    const int w    = tid >> 6;
    const int lg   = lane >> 4;
    const int lr   = lane & 15;

    __shared__ ushort Ks[64 * 72];
    __shared__ ushort Vt[64 * 72];
    __shared__ ushort Ps[64 * 72];

    const size_t base = (size_t)bb * Tc * 3072 + (size_t)hh * 64;

    // Q A-fragments in registers: rows qt*64 + w*16 + lr, k-chunks lg*8 (+32)
    bf16x8 qf[2];
    {
        const ushort* qrow = qkv + base + (size_t)(qt * 64 + w * 16 + lr) * 3072;
        qf[0] = *(const bf16x8*)(qrow + lg * 8);
        qf[1] = *(const bf16x8*)(qrow + 32 + lg * 8);
    }

    float mreg[4], lreg[4];
    f32x4 oacc[4];
#pragma unroll
    for (int r = 0; r < 4; ++r) { mreg[r] = -1e30f; lreg[r] = 0.0f; }
#pragma unroll
    for (int d = 0; d < 4; ++d) oacc[d] = (f32x4){0.f, 0.f, 0.f, 0.f};

    for (int kt = 0; kt < 16; ++kt) {
        __syncthreads();
        // stage K [key][d] and V^T [d][key]; 512 8-elem chunks, 2 per thread
#pragma unroll
        for (int j = 0; j < 2; ++j) {
            const int c   = tid + j * 256;
            const int key = c >> 3;
            const int dc  = c & 7;
            const ushort* krow = qkv + base + (size_t)(kt * 64 + key) * 3072;
            const uint4 kv = *(const uint4*)(krow + Hc + dc * 8);
            const uint4 vv = *(const uint4*)(krow + 2 * Hc + dc * 8);
            *(uint4*)&Ks[key * 72 + dc * 8] = kv;
            union { uint4 v; ushort u[8]; } cv;
            cv.v = vv;
#pragma unroll
            for (int jj = 0; jj < 8; ++jj) Vt[(dc * 8 + jj) * 72 + key] = cv.u[jj];
        }
        __syncthreads();

        // ---- QK^T: S[16q x 64k] per wave ----
        f32x4 s[4];
#pragma unroll
        for (int f = 0; f < 4; ++f) s[f] = (f32x4){0.f, 0.f, 0.f, 0.f};
#pragma unroll
        for (int ks = 0; ks < 2; ++ks) {
#pragma unroll
            for (int f = 0; f < 4; ++f) {
                const bf16x8 kf = *(const bf16x8*)&Ks[(f * 16 + lr) * 72 + ks * 32 + lg * 8];
                s[f] = __builtin_amdgcn_mfma_f32_16x16x32_bf16(qf[ks], kf, s[f], 0, 0, 0);
            }
        }

        // ---- online softmax (per reg r -> q-row w*16 + lg*4 + r) ----
#pragma unroll
        for (int r = 0; r < 4; ++r) {
            float s0 = s[0][r] * 0.125f, s1 = s[1][r] * 0.125f;
            float s2 = s[2][r] * 0.125f, s3 = s[3][r] * 0.125f;
            float mx = fmaxf(fmaxf(s0, s1), fmaxf(s2, s3));
#pragma unroll
            for (int msk = 1; msk < 16; msk <<= 1) mx = fmaxf(mx, __shfl_xor(mx, msk));
            const float mn = fmaxf(mreg[r], mx);
            const float sc = expf(mreg[r] - mn);
            const float p0 = expf(s0 - mn), p1 = expf(s1 - mn);
            const float p2 = expf(s2 - mn), p3 = expf(s3 - mn);
            float rs = p0 + p1 + p2 + p3;
#pragma unroll
            for (int msk = 1; msk < 16; msk <<= 1) rs += __shfl_xor(rs, msk);
            lreg[r] = lreg[r] * sc + rs;
            mreg[r] = mn;
#pragma unroll
            for (int d = 0; d < 4; ++d) oacc[d][r] *= sc;
            const int prow = (w * 16 + lg * 4 + r) * 72;
            Ps[prow + 0 * 16 + lr] = f2bf(p0);
            Ps[prow + 1 * 16 + lr] = f2bf(p1);
            Ps[prow + 2 * 16 + lr] = f2bf(p2);
            Ps[prow + 3 * 16 + lr] = f2bf(p3);
        }

        // ---- PV: O[16q x 64d] += P @ V  (P rows wave-private, no barrier) ----
#pragma unroll
        for (int ks = 0; ks < 2; ++ks) {
            const bf16x8 pa = *(const bf16x8*)&Ps[(w * 16 + lr) * 72 + ks * 32 + lg * 8];
#pragma unroll
            for (int d = 0; d < 4; ++d) {
                const bf16x8 vf = *(const bf16x8*)&Vt[(d * 16 + lr) * 72 + ks * 32 + lg * 8];
                oacc[d] = __builtin_amdgcn_mfma_f32_16x16x32_bf16(pa, vf, oacc[d], 0, 0, 0);
            }
        }
    }

    // ---- epilogue: row = q, col = d (C layout: col=lr, row=lg*4+r) ----
#pragma unroll
    for (int r = 0; r < 4; ++r) {
        const float inv = 1.0f / lreg[r];
        const size_t grow = (size_t)(bb * Tc + qt * 64 + w * 16 + lg * 4 + r) * Hc + hh * 64;
#pragma unroll
        for (int d = 0; d < 4; ++d)
            o[grow + d * 16 + lr] = f2bf(oacc[d][r] * inv);
    }
}

// ---------------------------- MoE gating -----------------------------------
__global__ __launch_bounds__(256) void gate_kernel(const float* __restrict__ h2,
                                                   const float* __restrict__ wg,
                                                   int* __restrict__ eidx,
                                                   float* __restrict__ gvr) {
    const int s = blockIdx.x;
    const int tid = threadIdx.x;
    const float4 hv = ((const float4*)(h2 + (size_t)s * Hc))[tid];
    const float hx[4] = {hv.x, hv.y, hv.z, hv.w};
    float p[8];
#pragma unroll
    for (int e2 = 0; e2 < 8; ++e2) p[e2] = 0.0f;
#pragma unroll
    for (int i = 0; i < 4; ++i) {
        const int k = tid * 4 + i;
        const float4 w0 = *(const float4*)(wg + (size_t)k * 8);
        const float4 w1 = *(const float4*)(wg + (size_t)k * 8 + 4);
        p[0] = fmaf(hx[i], w0.x, p[0]);
        p[1] = fmaf(hx[i], w0.y, p[1]);
        p[2] = fmaf(hx[i], w0.z, p[2]);
        p[3] = fmaf(hx[i], w0.w, p[3]);
        p[4] = fmaf(hx[i], w1.x, p[4]);
        p[5] = fmaf(hx[i], w1.y, p[5]);
        p[6] = fmaf(hx[i], w1.z, p[6]);
        p[7] = fmaf(hx[i], w1.w, p[7]);
    }
#pragma unroll
    for (int e2 = 0; e2 < 8; ++e2)
#pragma unroll
        for (int msk = 1; msk < 64; msk <<= 1) p[e2] += __shfl_xor(p[e2], msk);
    __shared__ float lg[4][8];
    if ((tid & 63) == 0) {
#pragma unroll
        for (int e2 = 0; e2 < 8; ++e2) lg[tid >> 6][e2] = p[e2];
    }
    __syncthreads();
    if (tid == 0) {
        float l[8];
#pragma unroll
        for (int e2 = 0; e2 < 8; ++e2) l[e2] = lg[0][e2] + lg[1][e2] + lg[2][e2] + lg[3][e2];
        int best = 0;
        float bm = l[0];
#pragma unroll
        for (int e2 = 1; e2 < 8; ++e2)
            if (l[e2] > bm) { bm = l[e2]; best = e2; }
        float se = 0.0f;
#pragma unroll
        for (int e2 = 0; e2 < 8; ++e2) se += expf(l[e2] - bm);
        eidx[s] = best;
        gvr[s] = 1.0f / se;
    }
}

// ---------------------------- MoE routing scan (order-dependent) -----------
__global__ __launch_bounds__(256) void route_kernel(const int* __restrict__ eidx,
                                                    const float* __restrict__ gvr,
                                                    int* __restrict__ posc,
                                                    float* __restrict__ gval,
                                                    int* __restrict__ s2t,
                                                    int* __restrict__ counts) {
    __shared__ int running[8];
    __shared__ unsigned long long wb[8][4];
    const int tid = threadIdx.x;
    const int wave = tid >> 6;
    const int lane = tid & 63;
    if (tid < 8) running[tid] = 0;
    __syncthreads();
    for (int chunk = 0; chunk < Sc / 256; ++chunk) {
        const int s = chunk * 256 + tid;
        const int e = eidx[s];
#pragma unroll
        for (int ex = 0; ex < 8; ++ex) {
            const unsigned long long bl = __ballot(e == ex);
            if (lane == 0) wb[ex][wave] = bl;
        }
        __syncthreads();
        int before = running[e];
#pragma unroll
        for (int w = 0; w < 4; ++w) {
            const unsigned long long bw = wb[e][w];
            if (w < wave) before += __popcll(bw);
            else if (w == wave) before += __popcll(bw & ((1ull << lane) - 1ull));
        }
        const int pos = before;
        const int keep = pos < CAPc;
        posc[s] = keep ? pos : (CAPc - 1);
        gval[s] = keep ? gvr[s] : 0.0f;
        if (keep) s2t[e * CAPc + pos] = s;
        __syncthreads();
        if (tid < 8) {
            int tot = 0;
#pragma unroll
            for (int w = 0; w < 4; ++w) tot += __popcll(wb[tid][w]);
            running[tid] += tot;
        }
        __syncthreads();
    }
    if (tid < 8) counts[tid] = running[tid];
}

// ---------------------------- MoE dispatch (fp32 -> bf16) -------------------
__global__ __launch_bounds__(256) void dispatch_kernel(const float* __restrict__ h2,
                                                       const int* __restrict__ s2t,
                                                       const int* __restrict__ counts,
                                                       ushort* __restrict__ disp) {
    const int slot = blockIdx.x;
    const int e = slot >> 9;
    const int c = slot & (CAPc - 1);
    int cnt = counts[e];
    cnt = cnt > CAPc ? CAPc : cnt;
    ushort4* dst = (ushort4*)(disp + (size_t)slot * Hc);
    if (c < cnt) {
        const int s = s2t[slot];
        const float4 v = ((const float4*)(h2 + (size_t)s * Hc))[threadIdx.x];
        dst[threadIdx.x] = pack4(v.x, v.y, v.z, v.w);
    } else {
        dst[threadIdx.x] = make_ushort4(0, 0, 0, 0);
    }
}

// ---------------------------- MoE gather + residual ------------------------
__global__ __launch_bounds__(256) void gather_kernel(const float* __restrict__ x1,
                                                     const float* __restrict__ eout,
                                                     const int* __restrict__ eidx,
                                                     const int* __restrict__ posc,
                                                     const float* __restrict__ gval,
                                                     float* __restrict__ out) {
    const int s = blockIdx.x;
    const float g = gval[s];
    const int slot = eidx[s] * CAPc + posc[s];
    const float4 a = ((const float4*)(x1 + (size_t)s * Hc))[threadIdx.x];
    const float4 b = ((const float4*)(eout + (size_t)slot * Hc))[threadIdx.x];
    float4 r;
    r.x = a.x + b.x * g;
    r.y = a.y + b.y * g;
    r.z = a.z + b.z * g;
    r.w = a.w + b.w * g;
    ((float4*)(out + (size_t)s * Hc))[threadIdx.x] = r;
}

// ---------------------------------------------------------------------------
extern "C" void kernel_launch(void* const* d_in, const int* in_sizes, int n_in,
                              void* d_out, int out_size, void* d_ws, size_t ws_size,
                              hipStream_t stream) {
    const float* x     = (const float*)d_in[0];
    const float* ln1_w = (const float*)d_in[1];
    const float* ln1_b = (const float*)d_in[2];
    const float* in_w  = (const float*)d_in[3];
    const float* in_b  = (const float*)d_in[4];
    const float* out_w = (const float*)d_in[5];
    const float* out_b = (const float*)d_in[6];
    const float* ln2_w = (const float*)d_in[7];
    const float* ln2_b = (const float*)d_in[8];
    const float* wg    = (const float*)d_in[9];
    const float* w1    = (const float*)d_in[10];
    const float* b1    = (const float*)d_in[11];
    const float* w2    = (const float*)d_in[12];
    const float* b2    = (const float*)d_in[13];
    float* out = (float*)d_out;
    float* ws  = (float*)d_ws;

    const size_t SH = (size_t)Sc * Hc;  // 4M elems
    // Workspace (72 MB):
    //  region0 [12M f32 = 48MB]: qkv bf16 (12M u16 = 24MB) -> hmid bf16 (32MB)
    //  region1 [ 2M f32 =  8MB]: h/attno/disp bf16 (4M u16, sequential reuse)
    //  region2 [ 4M f32 = 16MB]: h2 fp32 -> eout fp32
    //  x1 lives in d_out.
    ushort* qkv_u  = (ushort*)ws;              // 12M ushorts
    ushort* hmid_u = (ushort*)ws;              // 16M ushorts (same region, later)
    float*  r1     = ws + 3 * SH;
    ushort* hA     = (ushort*)r1;              // 4M ushorts: h -> attno -> disp
    float*  r2     = r1 + SH / 2;
    float*  h2     = r2;
    float*  eout   = r2;
    float*  smallf = r2 + SH;
    float* gvr  = smallf;
    float* gval = gvr + Sc;
    int* eidx   = (int*)(gval + Sc);
    int* posc   = eidx + Sc;
    int* s2t    = posc + Sc;
    int* counts = s2t + Ec * CAPc;

    float* x1 = out;

    // 1. LN1 -> h (bf16)
    ln_kernel<1><<<Sc, 256, 0, stream>>>(x, ln1_w, ln1_b, hA);
    // 2. qkv = h @ in_w^T + in_b              [4096,3072] bf16 out
    mgemm<0, 0, 1><<<dim3(24, 32, 1), 256, 0, stream>>>(
        hA, in_w, in_b, nullptr, qkv_u, Sc, 3 * Hc, Hc, 0, 0, 0, 0);
    // 3. bf16 MFMA flash attention -> attno (bf16)
    mattn<<<dim3(Tc / 64, Bc * NHc), 256, 0, stream>>>(qkv_u, hA);
    // 4. x1 = attno @ out_w^T + out_b + x     [4096,1024] fp32 out (d_out)
    mgemm<0, 2, 0><<<dim3(8, 32, 1), 256, 0, stream>>>(
        hA, out_w, out_b, x, x1, Sc, Hc, Hc, 0, 0, 0, 0);
    // 5. LN2 -> h2 (fp32)
    ln_kernel<0><<<Sc, 256, 0, stream>>>(x1, ln2_w, ln2_b, h2);
    // 6. gating
    gate_kernel<<<Sc, 256, 0, stream>>>(h2, wg, eidx, gvr);
    // 7. order-dependent routing scan (single block)
    route_kernel<<<1, 256, 0, stream>>>(eidx, gvr, posc, gval, s2t, counts);
    // 8. dispatch into [E,CAP,H] bf16 (zero-fills unused slots)
    dispatch_kernel<<<Ec * CAPc, 256, 0, stream>>>(h2, s2t, counts, hA);
    // 9. hmid = gelu(disp @ w1 + b1)          [E,512,4096] bf16 out
    mgemm<1, 1, 1><<<dim3(32, 4, Ec), 256, 0, stream>>>(
        hA, w1, b1, nullptr, hmid_u, CAPc, FFc, Hc,
        (long long)CAPc * Hc, (long long)Hc * FFc, (long long)CAPc * FFc, FFc);
    // 10. eout = hmid @ w2 + b2               [E,512,1024] fp32 out
    mgemm<1, 0, 0><<<dim3(8, 4, Ec), 256, 0, stream>>>(
        hmid_u, w2, b2, nullptr, eout, CAPc, Hc, FFc,
        (long long)CAPc * FFc, (long long)FFc * Hc, (long long)CAPc * Hc, Hc);
    // 11. out = x1 + eout[route] * gval
    gather_kernel<<<Sc, 256, 0, stream>>>(x1, eout, eidx, posc, gval, out);
}